// Round 8
// baseline (272.901 us; speedup 1.0000x reference)
//
#include <hip/hip_runtime.h>

#define T_TOK 2048
#define DIMX  1024
#define AHX   2048
#define HIDX  1024
#define NEXP  8
#define NHEAD 16
#define HD    128

typedef unsigned short us;
typedef short bf16x8 __attribute__((ext_vector_type(8)));
typedef float f32x4  __attribute__((ext_vector_type(4)));

__device__ __forceinline__ us f2bf(float f){
  unsigned int u = __builtin_bit_cast(unsigned int, f);
  u += 0x7FFFu + ((u >> 16) & 1u);          // RNE
  return (us)(u >> 16);
}
__device__ __forceinline__ float bf2f(us h){
  unsigned int u = ((unsigned int)h) << 16;
  return __builtin_bit_cast(float, u);
}
__device__ __forceinline__ float gelu_exact(float x){
  return 0.5f * x * (1.0f + erff(x * 0.70710678118654752440f));
}
__device__ __forceinline__ void gload16(const us* g, us* l){
  __builtin_amdgcn_global_load_lds((const __attribute__((address_space(1))) unsigned int*)g,
                                   (__attribute__((address_space(3))) unsigned int*)l, 16, 0, 0);
}

// ------------- pre: split_cast(x) + rmsnorm(xproj) + transpose wq/wk + transpose/split w1/w2 ---
__global__ __launch_bounds__(256) void k_pre(const float* __restrict__ x,
                                             us* __restrict__ xh, us* __restrict__ xl,
                                             const float* __restrict__ xproj,
                                             const float* __restrict__ anw,
                                             us* __restrict__ xn,
                                             const float* __restrict__ wq,
                                             const float* __restrict__ wk,
                                             us* __restrict__ wqkT,
                                             const float* __restrict__ w1,
                                             const float* __restrict__ w2,
                                             us* __restrict__ w1h, us* __restrict__ w1l,
                                             us* __restrict__ w2h, us* __restrict__ w2l){
  __shared__ float tile[32][33];
  __shared__ float ps[4];
  int bx = blockIdx.x, t = threadIdx.x;
  if (bx < 8192){
    int i = bx * 256 + t;
    float v = x[i];
    us h = f2bf(v);
    xh[i] = h;
    xl[i] = f2bf(v - bf2f(h));
    return;
  }
  if (bx < 10240){
    int row = bx - 8192;
    const float* p = xproj + (size_t)row * AHX;
    float v[8];
    *(float4*)&v[0] = *(const float4*)(p + t * 8);
    *(float4*)&v[4] = *(const float4*)(p + t * 8 + 4);
    float s = 0.f;
    #pragma unroll
    for (int i = 0; i < 8; i++) s += v[i] * v[i];
    #pragma unroll
    for (int m = 1; m < 64; m <<= 1) s += __shfl_xor(s, m);
    if ((t & 63) == 0) ps[t >> 6] = s;
    __syncthreads();
    float tot = ps[0] + ps[1] + ps[2] + ps[3];
    float rs = rsqrtf(tot * (1.0f / AHX) + 1e-6f);
    #pragma unroll
    for (int i = 0; i < 8; i++)
      xn[(size_t)row * AHX + t * 8 + i] = f2bf(v[i] * rs * anw[t * 8 + i]);
    return;
  }
  int tx = t & 31, ty = t >> 5;   // 32x8
  if (bx < 18432){
    int sub = bx - 10240;
    const float* in = (sub >> 12) ? wk : wq;
    us* o = wqkT + (size_t)(sub >> 12) * AHX * AHX;
    int rem = sub & 4095;
    int tbx = (rem & 63) * 32, tby = (rem >> 6) * 32;
    #pragma unroll
    for (int i = 0; i < 32; i += 8)
      tile[ty + i][tx] = in[(size_t)(tby + ty + i) * AHX + tbx + tx];
    __syncthreads();
    #pragma unroll
    for (int i = 0; i < 32; i += 8)
      o[(size_t)(tbx + ty + i) * AHX + tby + tx] = f2bf(tile[tx][ty + i]);
    return;
  }
  {
    int sub = bx - 18432;
    const float* in = (sub >> 10) ? w2 : w1;
    us* oh = (sub >> 10) ? w2h : w1h;
    us* ol = (sub >> 10) ? w2l : w1l;
    int rem = sub & 1023;
    int tbx = (rem & 31) * 32, tby = (rem >> 5) * 32;
    #pragma unroll
    for (int i = 0; i < 32; i += 8)
      tile[ty + i][tx] = in[(size_t)(tby + ty + i) * HIDX + tbx + tx];
    __syncthreads();
    #pragma unroll
    for (int i = 0; i < 32; i += 8){
      float v = tile[tx][ty + i];
      us h = f2bf(v);
      size_t o = (size_t)(tbx + ty + i) * DIMX + tby + tx;
      oh[o] = h;
      ol[o] = f2bf(v - bf2f(h));
    }
  }
}

// ------- fused Q|K projection GEMM + per-head rmsnorm epilogue, 8 waves -------
__global__ __launch_bounds__(512) void k_gemm_qk(
    const us* __restrict__ A, const us* __restrict__ B,
    const float* __restrict__ bq, const float* __restrict__ bk,
    const float* __restrict__ qnw, const float* __restrict__ knw,
    us* __restrict__ Qnn, us* __restrict__ Knn, int K)
{
  __shared__ __align__(16) us sA[2][128 * 64];
  __shared__ __align__(16) us sB[2][128 * 64];
  __shared__ float sums[128][4];
  int tid = threadIdx.x;
  int bm = blockIdx.y * 128;
  int bnB = blockIdx.x * 128;
  int w = tid >> 6, l = tid & 63;
  int wm = (w >> 2) * 64, wn = (w & 3) * 32;
  int lhi = l >> 4, llo = l & 15;
  int srow = l >> 3;
  int scol = ((l & 7) ^ srow) * 8;
  int swz = llo & 7;

  const us* pA = &A[(size_t)(bm + w * 16 + srow) * K + scol];
  const us* pB = &B[(size_t)(bnB + w * 16 + srow) * K + scol];

  f32x4 acc[4][2] = {};

  #pragma unroll
  for (int i = 0; i < 2; i++){
    gload16(pA + (size_t)i * 8 * K, &sA[0][(w * 16 + i * 8) * 64]);
    gload16(pB + (size_t)i * 8 * K, &sB[0][(w * 16 + i * 8) * 64]);
  }
  __syncthreads();

  int cur = 0;
  for (int k0 = 0; k0 < K; k0 += 64){
    if (k0 + 64 < K){
      #pragma unroll
      for (int i = 0; i < 2; i++){
        gload16(pA + (size_t)i * 8 * K + k0 + 64, &sA[cur ^ 1][(w * 16 + i * 8) * 64]);
        gload16(pB + (size_t)i * 8 * K + k0 + 64, &sB[cur ^ 1][(w * 16 + i * 8) * 64]);
      }
    }
    bf16x8 af[2][4], bfr[2][2];
    #pragma unroll
    for (int kk = 0; kk < 2; kk++){
      int ca = ((kk * 4 + lhi) ^ swz) * 8;
      #pragma unroll
      for (int m = 0; m < 4; m++)
        af[kk][m] = *(const bf16x8*)&sA[cur][(wm + m * 16 + llo) * 64 + ca];
      #pragma unroll
      for (int n = 0; n < 2; n++)
        bfr[kk][n] = *(const bf16x8*)&sB[cur][(wn + n * 16 + llo) * 64 + ca];
    }
    #pragma unroll
    for (int kk = 0; kk < 2; kk++)
      #pragma unroll
      for (int m = 0; m < 4; m++)
        #pragma unroll
        for (int n = 0; n < 2; n++)
          acc[m][n] = __builtin_amdgcn_mfma_f32_16x16x32_bf16(af[kk][m], bfr[kk][n], acc[m][n], 0, 0, 0);
    __syncthreads();
    cur ^= 1;
  }

  bool isq = blockIdx.x < 16;
  const float* bias = isq ? bq : bk;
  const float* nw   = isq ? qnw : knw;
  us* outp = isq ? Qnn : Knn;
  int hcol0 = (blockIdx.x & 15) * 128;

  #pragma unroll
  for (int n = 0; n < 2; n++){
    float bv = bias[hcol0 + wn + n * 16 + llo];
    #pragma unroll
    for (int m = 0; m < 4; m++)
      #pragma unroll
      for (int j = 0; j < 4; j++) acc[m][n][j] += bv;
  }
  #pragma unroll
  for (int m = 0; m < 4; m++)
    #pragma unroll
    for (int j = 0; j < 4; j++){
      float p = 0.f;
      #pragma unroll
      for (int n = 0; n < 2; n++) p += acc[m][n][j] * acc[m][n][j];
      p += __shfl_xor(p, 1); p += __shfl_xor(p, 2);
      p += __shfl_xor(p, 4); p += __shfl_xor(p, 8);
      if (llo == 0) sums[wm + m * 16 + lhi * 4 + j][w & 3] = p;
    }
  __syncthreads();
  #pragma unroll
  for (int m = 0; m < 4; m++)
    #pragma unroll
    for (int j = 0; j < 4; j++){
      int row = wm + m * 16 + lhi * 4 + j;
      float rs = rsqrtf((sums[row][0] + sums[row][1] + sums[row][2] + sums[row][3]) * (1.0f / HD) + 1e-6f);
      #pragma unroll
      for (int n = 0; n < 2; n++){
        int col = wn + n * 16 + llo;
        outp[(size_t)(bm + row) * AHX + hcol0 + col] = f2bf(acc[m][n][j] * rs * nw[col]);
      }
    }
}

// -------- MLP GEMM: all-register (no LDS, no barriers), split-bf16 fp32 emulation --------
// A,B fragments loaded directly global->VGPR (both L2-resident). 64x64 tile, 4 waves.
template<int EPI>
__global__ __launch_bounds__(256) void k_mlp(
    const us* __restrict__ Ah_, const us* __restrict__ Al_,
    const us* __restrict__ Bh_, const us* __restrict__ Bl_,
    const float* __restrict__ bias,
    float* __restrict__ Cf, us* __restrict__ Ch, us* __restrict__ Cl,
    int N, int K)
{
  int tid = threadIdx.x;
  int w = tid >> 6, l = tid & 63;
  int lhi = l >> 4, llo = l & 15;
  int bm = blockIdx.y * 64 + (w >> 1) * 32;
  int bn = blockIdx.x * 64 + (w & 1) * 32;

  const us* pAh = Ah_ + (size_t)(bm + llo) * K + lhi * 8;
  const us* pAl = Al_ + (size_t)(bm + llo) * K + lhi * 8;
  const us* pBh = Bh_ + (size_t)(bn + llo) * K + lhi * 8;
  const us* pBl = Bl_ + (size_t)(bn + llo) * K + lhi * 8;

  f32x4 acc[2][2] = {};

  for (int k0 = 0; k0 < K; k0 += 64){
    bf16x8 ah[2][2], al[2][2], bh[2][2], bl[2][2];   // [row/col group][kk]
    #pragma unroll
    for (int m = 0; m < 2; m++)
      #pragma unroll
      for (int kk = 0; kk < 2; kk++){
        size_t oa = (size_t)(m * 16) * K + k0 + kk * 32;
        ah[m][kk] = *(const bf16x8*)(pAh + oa);
        al[m][kk] = *(const bf16x8*)(pAl + oa);
        bh[m][kk] = *(const bf16x8*)(pBh + oa);
        bl[m][kk] = *(const bf16x8*)(pBl + oa);
      }
    #pragma unroll
    for (int kk = 0; kk < 2; kk++)
      #pragma unroll
      for (int m = 0; m < 2; m++)
        #pragma unroll
        for (int n = 0; n < 2; n++){
          acc[m][n] = __builtin_amdgcn_mfma_f32_16x16x32_bf16(ah[m][kk], bh[n][kk], acc[m][n], 0, 0, 0);
          acc[m][n] = __builtin_amdgcn_mfma_f32_16x16x32_bf16(ah[m][kk], bl[n][kk], acc[m][n], 0, 0, 0);
          acc[m][n] = __builtin_amdgcn_mfma_f32_16x16x32_bf16(al[m][kk], bh[n][kk], acc[m][n], 0, 0, 0);
        }
  }

  #pragma unroll
  for (int m = 0; m < 2; m++)
    #pragma unroll
    for (int n = 0; n < 2; n++){
      int col = bn + n * 16 + llo;
      float bv = bias[col];
      #pragma unroll
      for (int j = 0; j < 4; j++){
        int row = bm + m * 16 + lhi * 4 + j;
        float v = acc[m][n][j] + bv;
        size_t off = (size_t)row * N + col;
        if constexpr (EPI == 1){
          float g = gelu_exact(v);
          us hh = f2bf(g);
          Ch[off] = hh;
          Cl[off] = f2bf(g - bf2f(hh));
        } else {
          Cf[off] = gelu_exact(v);
        }
      }
    }
}

// ------- fused scores: pass1 Z (in registers) + pass2 importance column sums -------
// One block per (128-q-block, head); 8 waves; loops all 16 K-tiles twice.
__global__ __launch_bounds__(512) void k_scores(const us* __restrict__ Qn,
                                                const us* __restrict__ Kn,
                                                float* __restrict__ imp_part){
  __shared__ __align__(16) us sK[2][128 * 128];
  __shared__ float simp[8][128];
  int h = blockIdx.y;
  int qb = blockIdx.x * 128;
  int tid = threadIdx.x, w = tid >> 6, l = tid & 63;
  int lhi = l >> 4, llo = l & 15;
  int wq = qb + w * 16;
  const float scale = 0.08838834764831845f;

  auto stageK = [&](int buf, int kt){
    #pragma unroll
    for (int i = 0; i < 4; i++){
      int rb = w * 16 + i * 4;
      int r = rb + lhi;
      int c = (llo ^ (r & 7)) * 8;
      gload16(&Kn[(size_t)(kt + r) * AHX + h * HD + c], &sK[buf][rb * 128]);
    }
  };

  bf16x8 qf[4];
  #pragma unroll
  for (int kk = 0; kk < 4; kk++)
    qf[kk] = *(const bf16x8*)&Qn[(size_t)(wq + llo) * AHX + h * HD + kk * 32 + lhi * 8];

  float rz[4] = {};
  float rcv[4] = {};

  stageK(0, 0);
  __syncthreads();

  for (int t = 0; t < 32; t++){
    int cur = t & 1;
    if (t + 1 < 32) stageK(cur ^ 1, ((t + 1) & 15) * 128);
    f32x4 acc[8] = {};
    #pragma unroll
    for (int n = 0; n < 8; n++){
      int row = n * 16 + llo;
      #pragma unroll
      for (int kk = 0; kk < 4; kk++){
        bf16x8 kf = *(const bf16x8*)&sK[cur][row * 128 + ((kk * 32 + lhi * 8) ^ ((llo & 7) << 3))];
        acc[n] = __builtin_amdgcn_mfma_f32_16x16x32_bf16(qf[kk], kf, acc[n], 0, 0, 0);
      }
    }
    if (t < 16){
      #pragma unroll
      for (int j = 0; j < 4; j++){
        float s = 0.f;
        #pragma unroll
        for (int n = 0; n < 8; n++) s += __expf(acc[n][j] * scale);
        rz[j] += s;
      }
      if (t == 15){
        #pragma unroll
        for (int j = 0; j < 4; j++){
          float s = rz[j];
          s += __shfl_xor(s, 1); s += __shfl_xor(s, 2);
          s += __shfl_xor(s, 4); s += __shfl_xor(s, 8);
          rcv[j] = 1.0f / ((float)NHEAD * s);
        }
      }
      __syncthreads();
    } else {
      #pragma unroll
      for (int n = 0; n < 8; n++){
        float s = 0.f;
        #pragma unroll
        for (int j = 0; j < 4; j++) s += __expf(acc[n][j] * scale) * rcv[j];
        s += __shfl_xor(s, 16);
        s += __shfl_xor(s, 32);
        if (l < 16) simp[w][n * 16 + l] = s;
      }
      __syncthreads();
      if (tid < 128){
        float tot = 0.f;
        #pragma unroll
        for (int ww = 0; ww < 8; ww++) tot += simp[ww][tid];
        imp_part[((size_t)blockIdx.x * NHEAD + h) * T_TOK + (t - 16) * 128 + tid] = tot;
      }
      __syncthreads();
    }
  }
}

// ---------------- final: impred [blocks 0..7] + router [8..519] ----------------
__global__ __launch_bounds__(256) void k_final(const float* __restrict__ imp_part,
                                               const float* __restrict__ h2,
                                               const float* __restrict__ w3,
                                               const float* __restrict__ b3,
                                               float* __restrict__ out){
  if (blockIdx.x < 8){
    int col = blockIdx.x * 256 + threadIdx.x;
    float s = 0.f;
    for (int r = 0; r < 256; r++) s += imp_part[(size_t)r * T_TOK + col];
    out[2 * T_TOK + col] = s;
    return;
  }
  int t = (blockIdx.x - 8) * 4 + (threadIdx.x >> 6);
  int l = threadIdx.x & 63;
  const float* hp = h2 + (size_t)t * HIDX;
  float acc[NEXP] = {};
  for (int i = l; i < HIDX; i += 64){
    float hv = hp[i];
    const float* wr = w3 + (size_t)i * NEXP;
    #pragma unroll
    for (int e = 0; e < NEXP; e++) acc[e] = fmaf(hv, wr[e], acc[e]);
  }
  #pragma unroll
  for (int mk = 1; mk < 64; mk <<= 1)
    #pragma unroll
    for (int e = 0; e < NEXP; e++) acc[e] += __shfl_xor(acc[e], mk);
  if (l == 0){
    float lg[NEXP], mx = -__builtin_inff();
    #pragma unroll
    for (int e = 0; e < NEXP; e++){ lg[e] = acc[e] + b3[e]; mx = fmaxf(mx, lg[e]); }
    float Z = 0.f, p[NEXP];
    #pragma unroll
    for (int e = 0; e < NEXP; e++){ p[e] = expf(lg[e] - mx); Z += p[e]; }
    float invZ = 1.0f / Z;
    #pragma unroll
    for (int e = 0; e < NEXP; e++) p[e] *= invZ;
    float gs[4];
    #pragma unroll
    for (int g = 0; g < 4; g++) gs[g] = fmaxf(p[2 * g], p[2 * g + 1]);
    int g1 = 0;
    #pragma unroll
    for (int g = 1; g < 4; g++) if (gs[g] > gs[g1]) g1 = g;
    int g2 = -1; float g2v = -__builtin_inff();
    #pragma unroll
    for (int g = 0; g < 4; g++) if (g != g1 && gs[g] > g2v){ g2v = gs[g]; g2 = g; }
    int best = 0; float bv = -__builtin_inff();
    #pragma unroll
    for (int e = 0; e < NEXP; e++){
      int g = e >> 1;
      if ((g == g1 || g == g2) && p[e] > bv){ bv = p[e]; best = e; }
    }
    out[t]         = bv;            // ROUTE_SCALE = 1.0
    out[T_TOK + t] = (float)best;   // idx as float
  }
}

// ---------------- driver ----------------
extern "C" void kernel_launch(void* const* d_in, const int* in_sizes, int n_in,
                              void* d_out, int out_size, void* d_ws, size_t ws_size,
                              hipStream_t stream){
  const float* x     = (const float*)d_in[0];
  const float* xproj = (const float*)d_in[1];
  const float* anw   = (const float*)d_in[2];
  const float* wq    = (const float*)d_in[3];
  const float* bq    = (const float*)d_in[4];
  const float* wk    = (const float*)d_in[5];
  const float* bk    = (const float*)d_in[6];
  const float* qnw   = (const float*)d_in[7];
  const float* knw   = (const float*)d_in[8];
  const float* w1    = (const float*)d_in[9];
  const float* b1    = (const float*)d_in[10];
  const float* w2    = (const float*)d_in[11];
  const float* b2    = (const float*)d_in[12];
  const float* w3    = (const float*)d_in[13];
  const float* b3    = (const float*)d_in[14];
  float* out = (float*)d_out;

  char* ws = (char*)d_ws;
  const size_t MB = 1024 * 1024;
  us* xn      = (us*)(ws);             // 8MB  [T][AHX] bf16
  us* wqkT    = (us*)(ws + 8 * MB);    // 16MB [4096][2048] bf16
  us* Qnn     = (us*)(ws + 24 * MB);   // 8MB
  us* Knn     = (us*)(ws + 32 * MB);   // 8MB
  float* imp_part = (float*)(ws + 42 * MB);  // 2MB [256][2048]
  us* xh      = (us*)(ws + 44 * MB);   // 4MB
  us* xl      = (us*)(ws + 48 * MB);   // 4MB
  us* w1Th    = (us*)(ws + 52 * MB);   // 2MB each
  us* w1Tl    = (us*)(ws + 54 * MB);
  us* w2Th    = (us*)(ws + 56 * MB);
  us* w2Tl    = (us*)(ws + 58 * MB);
  us* h1h     = (us*)(ws + 60 * MB);   // 4MB
  us* h1l     = (us*)(ws + 64 * MB);   // 4MB
  float* h2   = (float*)(ws + 68 * MB);// 8MB

  // all input prep in one kernel
  k_pre<<<20480, 256, 0, stream>>>(x, xh, xl, xproj, anw, xn,
                                   wq, wk, wqkT, w1, w2, w1Th, w1Tl, w2Th, w2Tl);

  // fused Q|K projection + per-head rmsnorm -> Qnn/Knn bf16 (8-wave blocks)
  k_gemm_qk<<<dim3(32, 16), 512, 0, stream>>>(xn, wqkT, bq, bk, qnw, knw, Qnn, Knn, AHX);

  // fused two-pass scores: Z in registers, importance partials out
  k_scores<<<dim3(16, NHEAD), 512, 0, stream>>>(Qnn, Knn, imp_part);

  // router MLP (all-register split-bf16 GEMMs)
  k_mlp<1><<<dim3(HIDX / 64, T_TOK / 64), 256, 0, stream>>>(
      xh, xl, w1Th, w1Tl, b1, nullptr, h1h, h1l, HIDX, DIMX);
  k_mlp<2><<<dim3(HIDX / 64, T_TOK / 64), 256, 0, stream>>>(
      h1h, h1l, w2Th, w2Tl, b2, h2, nullptr, nullptr, HIDX, HIDX);

  // importance reduction + router top-k
  k_final<<<8 + T_TOK / 4, 256, 0, stream>>>(imp_part, h2, w3, b3, out);

  (void)in_sizes; (void)n_in; (void)out_size; (void)ws_size;
}

// Round 9
// 213.884 us; speedup vs baseline: 1.2759x; 1.2759x over previous
//
#include <hip/hip_runtime.h>

#define T_TOK 2048
#define DIMX  1024
#define AHX   2048
#define HIDX  1024
#define NEXP  8
#define NHEAD 16
#define HD    128

typedef unsigned short us;
typedef short bf16x8 __attribute__((ext_vector_type(8)));
typedef float f32x4  __attribute__((ext_vector_type(4)));

__device__ __forceinline__ us f2bf(float f){
  unsigned int u = __builtin_bit_cast(unsigned int, f);
  u += 0x7FFFu + ((u >> 16) & 1u);          // RNE
  return (us)(u >> 16);
}
__device__ __forceinline__ float bf2f(us h){
  unsigned int u = ((unsigned int)h) << 16;
  return __builtin_bit_cast(float, u);
}
__device__ __forceinline__ float gelu_exact(float x){
  return 0.5f * x * (1.0f + erff(x * 0.70710678118654752440f));
}
__device__ __forceinline__ void gload16(const us* g, us* l){
  __builtin_amdgcn_global_load_lds((const __attribute__((address_space(1))) unsigned int*)g,
                                   (__attribute__((address_space(3))) unsigned int*)l, 16, 0, 0);
}

// ------------- pre: split_cast(x) + rmsnorm(xproj) + transpose wq/wk + transpose/split w1/w2 ---
__global__ __launch_bounds__(256) void k_pre(const float* __restrict__ x,
                                             us* __restrict__ xh, us* __restrict__ xl,
                                             const float* __restrict__ xproj,
                                             const float* __restrict__ anw,
                                             us* __restrict__ xn,
                                             const float* __restrict__ wq,
                                             const float* __restrict__ wk,
                                             us* __restrict__ wqkT,
                                             const float* __restrict__ w1,
                                             const float* __restrict__ w2,
                                             us* __restrict__ w1h, us* __restrict__ w1l,
                                             us* __restrict__ w2h, us* __restrict__ w2l){
  __shared__ float tile[32][33];
  __shared__ float ps[4];
  int bx = blockIdx.x, t = threadIdx.x;
  if (bx < 8192){
    int i = bx * 256 + t;
    float v = x[i];
    us h = f2bf(v);
    xh[i] = h;
    xl[i] = f2bf(v - bf2f(h));
    return;
  }
  if (bx < 10240){
    int row = bx - 8192;
    const float* p = xproj + (size_t)row * AHX;
    float v[8];
    *(float4*)&v[0] = *(const float4*)(p + t * 8);
    *(float4*)&v[4] = *(const float4*)(p + t * 8 + 4);
    float s = 0.f;
    #pragma unroll
    for (int i = 0; i < 8; i++) s += v[i] * v[i];
    #pragma unroll
    for (int m = 1; m < 64; m <<= 1) s += __shfl_xor(s, m);
    if ((t & 63) == 0) ps[t >> 6] = s;
    __syncthreads();
    float tot = ps[0] + ps[1] + ps[2] + ps[3];
    float rs = rsqrtf(tot * (1.0f / AHX) + 1e-6f);
    #pragma unroll
    for (int i = 0; i < 8; i++)
      xn[(size_t)row * AHX + t * 8 + i] = f2bf(v[i] * rs * anw[t * 8 + i]);
    return;
  }
  int tx = t & 31, ty = t >> 5;   // 32x8
  if (bx < 18432){
    int sub = bx - 10240;
    const float* in = (sub >> 12) ? wk : wq;
    us* o = wqkT + (size_t)(sub >> 12) * AHX * AHX;
    int rem = sub & 4095;
    int tbx = (rem & 63) * 32, tby = (rem >> 6) * 32;
    #pragma unroll
    for (int i = 0; i < 32; i += 8)
      tile[ty + i][tx] = in[(size_t)(tby + ty + i) * AHX + tbx + tx];
    __syncthreads();
    #pragma unroll
    for (int i = 0; i < 32; i += 8)
      o[(size_t)(tbx + ty + i) * AHX + tby + tx] = f2bf(tile[tx][ty + i]);
    return;
  }
  {
    int sub = bx - 18432;
    const float* in = (sub >> 10) ? w2 : w1;
    us* oh = (sub >> 10) ? w2h : w1h;
    us* ol = (sub >> 10) ? w2l : w1l;
    int rem = sub & 1023;
    int tbx = (rem & 31) * 32, tby = (rem >> 5) * 32;
    #pragma unroll
    for (int i = 0; i < 32; i += 8)
      tile[ty + i][tx] = in[(size_t)(tby + ty + i) * HIDX + tbx + tx];
    __syncthreads();
    #pragma unroll
    for (int i = 0; i < 32; i += 8){
      float v = tile[tx][ty + i];
      us h = f2bf(v);
      size_t o = (size_t)(tbx + ty + i) * DIMX + tby + tx;
      oh[o] = h;
      ol[o] = f2bf(v - bf2f(h));
    }
  }
}

// ------- fused Q|K projection GEMM + per-head rmsnorm epilogue, 8 waves -------
__global__ __launch_bounds__(512) void k_gemm_qk(
    const us* __restrict__ A, const us* __restrict__ B,
    const float* __restrict__ bq, const float* __restrict__ bk,
    const float* __restrict__ qnw, const float* __restrict__ knw,
    us* __restrict__ Qnn, us* __restrict__ Knn, int K)
{
  __shared__ __align__(16) us sA[2][128 * 64];
  __shared__ __align__(16) us sB[2][128 * 64];
  __shared__ float sums[128][4];
  int tid = threadIdx.x;
  int bm = blockIdx.y * 128;
  int bnB = blockIdx.x * 128;
  int w = tid >> 6, l = tid & 63;
  int wm = (w >> 2) * 64, wn = (w & 3) * 32;
  int lhi = l >> 4, llo = l & 15;
  int srow = l >> 3;
  int scol = ((l & 7) ^ srow) * 8;
  int swz = llo & 7;

  const us* pA = &A[(size_t)(bm + w * 16 + srow) * K + scol];
  const us* pB = &B[(size_t)(bnB + w * 16 + srow) * K + scol];

  f32x4 acc[4][2] = {};

  #pragma unroll
  for (int i = 0; i < 2; i++){
    gload16(pA + (size_t)i * 8 * K, &sA[0][(w * 16 + i * 8) * 64]);
    gload16(pB + (size_t)i * 8 * K, &sB[0][(w * 16 + i * 8) * 64]);
  }
  __syncthreads();

  int cur = 0;
  for (int k0 = 0; k0 < K; k0 += 64){
    if (k0 + 64 < K){
      #pragma unroll
      for (int i = 0; i < 2; i++){
        gload16(pA + (size_t)i * 8 * K + k0 + 64, &sA[cur ^ 1][(w * 16 + i * 8) * 64]);
        gload16(pB + (size_t)i * 8 * K + k0 + 64, &sB[cur ^ 1][(w * 16 + i * 8) * 64]);
      }
    }
    bf16x8 af[2][4], bfr[2][2];
    #pragma unroll
    for (int kk = 0; kk < 2; kk++){
      int ca = ((kk * 4 + lhi) ^ swz) * 8;
      #pragma unroll
      for (int m = 0; m < 4; m++)
        af[kk][m] = *(const bf16x8*)&sA[cur][(wm + m * 16 + llo) * 64 + ca];
      #pragma unroll
      for (int n = 0; n < 2; n++)
        bfr[kk][n] = *(const bf16x8*)&sB[cur][(wn + n * 16 + llo) * 64 + ca];
    }
    #pragma unroll
    for (int kk = 0; kk < 2; kk++)
      #pragma unroll
      for (int m = 0; m < 4; m++)
        #pragma unroll
        for (int n = 0; n < 2; n++)
          acc[m][n] = __builtin_amdgcn_mfma_f32_16x16x32_bf16(af[kk][m], bfr[kk][n], acc[m][n], 0, 0, 0);
    __syncthreads();
    cur ^= 1;
  }

  bool isq = blockIdx.x < 16;
  const float* bias = isq ? bq : bk;
  const float* nw   = isq ? qnw : knw;
  us* outp = isq ? Qnn : Knn;
  int hcol0 = (blockIdx.x & 15) * 128;

  #pragma unroll
  for (int n = 0; n < 2; n++){
    float bv = bias[hcol0 + wn + n * 16 + llo];
    #pragma unroll
    for (int m = 0; m < 4; m++)
      #pragma unroll
      for (int j = 0; j < 4; j++) acc[m][n][j] += bv;
  }
  #pragma unroll
  for (int m = 0; m < 4; m++)
    #pragma unroll
    for (int j = 0; j < 4; j++){
      float p = 0.f;
      #pragma unroll
      for (int n = 0; n < 2; n++) p += acc[m][n][j] * acc[m][n][j];
      p += __shfl_xor(p, 1); p += __shfl_xor(p, 2);
      p += __shfl_xor(p, 4); p += __shfl_xor(p, 8);
      if (llo == 0) sums[wm + m * 16 + lhi * 4 + j][w & 3] = p;
    }
  __syncthreads();
  #pragma unroll
  for (int m = 0; m < 4; m++)
    #pragma unroll
    for (int j = 0; j < 4; j++){
      int row = wm + m * 16 + lhi * 4 + j;
      float rs = rsqrtf((sums[row][0] + sums[row][1] + sums[row][2] + sums[row][3]) * (1.0f / HD) + 1e-6f);
      #pragma unroll
      for (int n = 0; n < 2; n++){
        int col = wn + n * 16 + llo;
        outp[(size_t)(bm + row) * AHX + hcol0 + col] = f2bf(acc[m][n][j] * rs * nw[col]);
      }
    }
}

// -------- MLP GEMM: C[M,N] = A*B^T (+bias, epilogue), split-bf16 fp32 emulation ---------
// BM=64, BN=64, BK=64; dbuf gload_lds, swizzled source/read. (round-7 proven form)
template<int EPI>
__global__ __launch_bounds__(256) void k_gemm_mlp(
    const us* __restrict__ Ah_, const us* __restrict__ Al_,
    const us* __restrict__ Bh_, const us* __restrict__ Bl_,
    const float* __restrict__ bias,
    float* __restrict__ Cf, us* __restrict__ Ch, us* __restrict__ Cl,
    int N, int K)
{
  __shared__ __align__(16) us sAh[2][64 * 64], sAl[2][64 * 64];
  __shared__ __align__(16) us sBh[2][64 * 64], sBl[2][64 * 64];
  int tid = threadIdx.x;
  int bm = blockIdx.y * 64, bn = blockIdx.x * 64;
  int w = tid >> 6, l = tid & 63;
  int wm = (w >> 1) * 32, wn = (w & 1) * 32;
  int lhi = l >> 4, llo = l & 15;
  int srow = l >> 3;
  int scol = ((l & 7) ^ srow) * 8;
  int swz = llo & 7;

  const us* pAh = &Ah_[(size_t)(bm + w * 8 + srow) * K + scol];
  const us* pAl = &Al_[(size_t)(bm + w * 8 + srow) * K + scol];
  const us* pBh = &Bh_[(size_t)(bn + w * 8 + srow) * K + scol];
  const us* pBl = &Bl_[(size_t)(bn + w * 8 + srow) * K + scol];

  f32x4 acc[2][2] = {};

  auto stage = [&](int buf, int k0){
    #pragma unroll
    for (int i = 0; i < 2; i++){
      int rb = (i * 32 + w * 8) * 64;
      gload16(pAh + (size_t)i * 32 * K + k0, &sAh[buf][rb]);
      gload16(pAl + (size_t)i * 32 * K + k0, &sAl[buf][rb]);
      gload16(pBh + (size_t)i * 32 * K + k0, &sBh[buf][rb]);
      gload16(pBl + (size_t)i * 32 * K + k0, &sBl[buf][rb]);
    }
  };

  stage(0, 0);
  __syncthreads();

  int cur = 0;
  for (int k0 = 0; k0 < K; k0 += 64){
    if (k0 + 64 < K) stage(cur ^ 1, k0 + 64);
    bf16x8 ah[2][2], al[2][2], bh[2][2], bl[2][2];
    #pragma unroll
    for (int kk = 0; kk < 2; kk++){
      int ca = ((kk * 4 + lhi) ^ swz) * 8;
      #pragma unroll
      for (int m = 0; m < 2; m++){
        ah[kk][m] = *(const bf16x8*)&sAh[cur][(wm + m * 16 + llo) * 64 + ca];
        al[kk][m] = *(const bf16x8*)&sAl[cur][(wm + m * 16 + llo) * 64 + ca];
        bh[kk][m] = *(const bf16x8*)&sBh[cur][(wn + m * 16 + llo) * 64 + ca];
        bl[kk][m] = *(const bf16x8*)&sBl[cur][(wn + m * 16 + llo) * 64 + ca];
      }
    }
    #pragma unroll
    for (int kk = 0; kk < 2; kk++)
      #pragma unroll
      for (int m = 0; m < 2; m++)
        #pragma unroll
        for (int n = 0; n < 2; n++){
          acc[m][n] = __builtin_amdgcn_mfma_f32_16x16x32_bf16(ah[kk][m], bh[kk][n], acc[m][n], 0, 0, 0);
          acc[m][n] = __builtin_amdgcn_mfma_f32_16x16x32_bf16(ah[kk][m], bl[kk][n], acc[m][n], 0, 0, 0);
          acc[m][n] = __builtin_amdgcn_mfma_f32_16x16x32_bf16(al[kk][m], bh[kk][n], acc[m][n], 0, 0, 0);
        }
    __syncthreads();
    cur ^= 1;
  }

  #pragma unroll
  for (int m = 0; m < 2; m++)
    #pragma unroll
    for (int n = 0; n < 2; n++){
      int col = bn + wn + n * 16 + llo;
      float bv = bias[col];
      #pragma unroll
      for (int j = 0; j < 4; j++){
        int row = bm + wm + m * 16 + lhi * 4 + j;
        float v = acc[m][n][j] + bv;
        size_t off = (size_t)row * N + col;
        if constexpr (EPI == 1){
          float g = gelu_exact(v);
          us hh = f2bf(g);
          Ch[off] = hh;
          Cl[off] = f2bf(g - bf2f(hh));
        } else {
          Cf[off] = gelu_exact(v);
        }
      }
    }
}

// ---------------- scores denominator: 8 waves x 32 q-rows, 4 K-tiles, dbuf ----------------
__global__ __launch_bounds__(512) void k_z(const us* __restrict__ Qn,
                                           const us* __restrict__ Kn,
                                           float* __restrict__ zpart){
  __shared__ __align__(16) us sK[2][128 * 128];
  int h = blockIdx.y;
  int qb = blockIdx.x * 256;
  int tid = threadIdx.x, w = tid >> 6, l = tid & 63;
  int lhi = l >> 4, llo = l & 15;
  int wq = qb + w * 32;
  const float scale = 0.08838834764831845f;

  auto stageK = [&](int buf, int kt){
    #pragma unroll
    for (int i = 0; i < 4; i++){
      int rb = w * 16 + i * 4;
      int r = rb + lhi;
      int c = (llo ^ (r & 7)) * 8;
      gload16(&Kn[(size_t)(kt + r) * AHX + h * HD + c], &sK[buf][rb * 128]);
    }
  };

  bf16x8 qf[2][4];
  #pragma unroll
  for (int m = 0; m < 2; m++)
    #pragma unroll
    for (int kk = 0; kk < 4; kk++)
      qf[m][kk] = *(const bf16x8*)&Qn[(size_t)(wq + m * 16 + llo) * AHX + h * HD + kk * 32 + lhi * 8];

  float rz[2][4] = {};
  int kt0 = blockIdx.z * 512;

  stageK(0, kt0);
  __syncthreads();

  #pragma unroll
  for (int t = 0; t < 4; t++){
    int cur = t & 1;
    if (t + 1 < 4) stageK(cur ^ 1, kt0 + (t + 1) * 128);
    f32x4 acc[2][8] = {};
    #pragma unroll
    for (int n = 0; n < 8; n++){
      int row = n * 16 + llo;
      #pragma unroll
      for (int kk = 0; kk < 4; kk++){
        bf16x8 kf = *(const bf16x8*)&sK[cur][row * 128 + ((kk * 32 + lhi * 8) ^ ((llo & 7) << 3))];
        acc[0][n] = __builtin_amdgcn_mfma_f32_16x16x32_bf16(qf[0][kk], kf, acc[0][n], 0, 0, 0);
        acc[1][n] = __builtin_amdgcn_mfma_f32_16x16x32_bf16(qf[1][kk], kf, acc[1][n], 0, 0, 0);
      }
    }
    #pragma unroll
    for (int m = 0; m < 2; m++)
      #pragma unroll
      for (int j = 0; j < 4; j++){
        float s = 0.f;
        #pragma unroll
        for (int n = 0; n < 8; n++) s += __expf(acc[m][n][j] * scale);
        rz[m][j] += s;
      }
    if (t + 1 < 4) __syncthreads();
  }
  #pragma unroll
  for (int m = 0; m < 2; m++)
    #pragma unroll
    for (int j = 0; j < 4; j++){
      float s = rz[m][j];
      s += __shfl_xor(s, 1); s += __shfl_xor(s, 2);
      s += __shfl_xor(s, 4); s += __shfl_xor(s, 8);
      if (llo == 0){
        int row = wq + m * 16 + lhi * 4 + j;
        zpart[(size_t)blockIdx.z * (NHEAD * T_TOK) + h * T_TOK + row] = s;
      }
    }
}

// ---------------- importance partials: 8 waves x 32 q-rows, inline rc gather ----------------
__global__ __launch_bounds__(512) void k_imp(const us* __restrict__ Qn,
                                             const us* __restrict__ Kn,
                                             const float* __restrict__ zpart,
                                             float* __restrict__ imp_part){
  __shared__ __align__(16) us sK[2][128 * 128];
  __shared__ float simp[8][128];
  int h = blockIdx.y;
  int qb = blockIdx.x * 256;
  int kt0 = blockIdx.z * 512;
  int tid = threadIdx.x, w = tid >> 6, l = tid & 63;
  int lhi = l >> 4, llo = l & 15;
  int wq = qb + w * 32;
  const float scale = 0.08838834764831845f;

  auto stageK = [&](int buf, int kt){
    #pragma unroll
    for (int i = 0; i < 4; i++){
      int rb = w * 16 + i * 4;
      int r = rb + lhi;
      int c = (llo ^ (r & 7)) * 8;
      gload16(&Kn[(size_t)(kt + r) * AHX + h * HD + c], &sK[buf][rb * 128]);
    }
  };

  bf16x8 qf[2][4];
  float rcv[2][4];
  #pragma unroll
  for (int m = 0; m < 2; m++)
    #pragma unroll
    for (int kk = 0; kk < 4; kk++)
      qf[m][kk] = *(const bf16x8*)&Qn[(size_t)(wq + m * 16 + llo) * AHX + h * HD + kk * 32 + lhi * 8];
  #pragma unroll
  for (int m = 0; m < 2; m++)
    #pragma unroll
    for (int j = 0; j < 4; j++){
      int row = wq + m * 16 + lhi * 4 + j;
      float zs = 0.f;
      #pragma unroll
      for (int p = 0; p < 4; p++) zs += zpart[(size_t)p * (NHEAD * T_TOK) + h * T_TOK + row];
      rcv[m][j] = 1.0f / ((float)NHEAD * zs);
    }

  stageK(0, kt0);
  __syncthreads();

  #pragma unroll
  for (int t = 0; t < 4; t++){
    int cur = t & 1;
    if (t + 1 < 4) stageK(cur ^ 1, kt0 + (t + 1) * 128);
    f32x4 acc[2][8] = {};
    #pragma unroll
    for (int n = 0; n < 8; n++){
      int row = n * 16 + llo;
      #pragma unroll
      for (int kk = 0; kk < 4; kk++){
        bf16x8 kf = *(const bf16x8*)&sK[cur][row * 128 + ((kk * 32 + lhi * 8) ^ ((llo & 7) << 3))];
        acc[0][n] = __builtin_amdgcn_mfma_f32_16x16x32_bf16(qf[0][kk], kf, acc[0][n], 0, 0, 0);
        acc[1][n] = __builtin_amdgcn_mfma_f32_16x16x32_bf16(qf[1][kk], kf, acc[1][n], 0, 0, 0);
      }
    }
    #pragma unroll
    for (int n = 0; n < 8; n++){
      float s = 0.f;
      #pragma unroll
      for (int m = 0; m < 2; m++)
        #pragma unroll
        for (int j = 0; j < 4; j++)
          s += __expf(acc[m][n][j] * scale) * rcv[m][j];
      s += __shfl_xor(s, 16);
      s += __shfl_xor(s, 32);
      if (l < 16) simp[w][n * 16 + l] = s;
    }
    __syncthreads();
    if (tid < 128){
      float tot = 0.f;
      #pragma unroll
      for (int ww = 0; ww < 8; ww++) tot += simp[ww][tid];
      imp_part[((size_t)blockIdx.x * NHEAD + h) * T_TOK + kt0 + t * 128 + tid] = tot;
    }
    __syncthreads();
  }
}

// ---------------- final: impred [blocks 0..7] + router [8..519] ----------------
__global__ __launch_bounds__(256) void k_final(const float* __restrict__ imp_part,
                                               const float* __restrict__ h2,
                                               const float* __restrict__ w3,
                                               const float* __restrict__ b3,
                                               float* __restrict__ out){
  if (blockIdx.x < 8){
    int col = blockIdx.x * 256 + threadIdx.x;
    float s = 0.f;
    for (int r = 0; r < 128; r++) s += imp_part[(size_t)r * T_TOK + col];
    out[2 * T_TOK + col] = s;
    return;
  }
  int t = (blockIdx.x - 8) * 4 + (threadIdx.x >> 6);
  int l = threadIdx.x & 63;
  const float* hp = h2 + (size_t)t * HIDX;
  float acc[NEXP] = {};
  for (int i = l; i < HIDX; i += 64){
    float hv = hp[i];
    const float* wr = w3 + (size_t)i * NEXP;
    #pragma unroll
    for (int e = 0; e < NEXP; e++) acc[e] = fmaf(hv, wr[e], acc[e]);
  }
  #pragma unroll
  for (int mk = 1; mk < 64; mk <<= 1)
    #pragma unroll
    for (int e = 0; e < NEXP; e++) acc[e] += __shfl_xor(acc[e], mk);
  if (l == 0){
    float lg[NEXP], mx = -__builtin_inff();
    #pragma unroll
    for (int e = 0; e < NEXP; e++){ lg[e] = acc[e] + b3[e]; mx = fmaxf(mx, lg[e]); }
    float Z = 0.f, p[NEXP];
    #pragma unroll
    for (int e = 0; e < NEXP; e++){ p[e] = expf(lg[e] - mx); Z += p[e]; }
    float invZ = 1.0f / Z;
    #pragma unroll
    for (int e = 0; e < NEXP; e++) p[e] *= invZ;
    float gs[4];
    #pragma unroll
    for (int g = 0; g < 4; g++) gs[g] = fmaxf(p[2 * g], p[2 * g + 1]);
    int g1 = 0;
    #pragma unroll
    for (int g = 1; g < 4; g++) if (gs[g] > gs[g1]) g1 = g;
    int g2 = -1; float g2v = -__builtin_inff();
    #pragma unroll
    for (int g = 0; g < 4; g++) if (g != g1 && gs[g] > g2v){ g2v = gs[g]; g2 = g; }
    int best = 0; float bv = -__builtin_inff();
    #pragma unroll
    for (int e = 0; e < NEXP; e++){
      int g = e >> 1;
      if ((g == g1 || g == g2) && p[e] > bv){ bv = p[e]; best = e; }
    }
    out[t]         = bv;            // ROUTE_SCALE = 1.0
    out[T_TOK + t] = (float)best;   // idx as float
  }
}

// ---------------- driver ----------------
extern "C" void kernel_launch(void* const* d_in, const int* in_sizes, int n_in,
                              void* d_out, int out_size, void* d_ws, size_t ws_size,
                              hipStream_t stream){
  const float* x     = (const float*)d_in[0];
  const float* xproj = (const float*)d_in[1];
  const float* anw   = (const float*)d_in[2];
  const float* wq    = (const float*)d_in[3];
  const float* bq    = (const float*)d_in[4];
  const float* wk    = (const float*)d_in[5];
  const float* bk    = (const float*)d_in[6];
  const float* qnw   = (const float*)d_in[7];
  const float* knw   = (const float*)d_in[8];
  const float* w1    = (const float*)d_in[9];
  const float* b1    = (const float*)d_in[10];
  const float* w2    = (const float*)d_in[11];
  const float* b2    = (const float*)d_in[12];
  const float* w3    = (const float*)d_in[13];
  const float* b3    = (const float*)d_in[14];
  float* out = (float*)d_out;

  char* ws = (char*)d_ws;
  const size_t MB = 1024 * 1024;
  us* xn      = (us*)(ws);             // 8MB  [T][AHX] bf16
  us* wqkT    = (us*)(ws + 8 * MB);    // 16MB [4096][2048] bf16
  us* Qnn     = (us*)(ws + 24 * MB);   // 8MB
  us* Knn     = (us*)(ws + 32 * MB);   // 8MB
  float* zpart    = (float*)(ws + 40 * MB);  // 512KB [4][16][2048]
  float* imp_part = (float*)(ws + 42 * MB);  // 1MB [128][2048]
  us* xh      = (us*)(ws + 44 * MB);   // 4MB
  us* xl      = (us*)(ws + 48 * MB);   // 4MB
  us* w1Th    = (us*)(ws + 52 * MB);   // 2MB each
  us* w1Tl    = (us*)(ws + 54 * MB);
  us* w2Th    = (us*)(ws + 56 * MB);
  us* w2Tl    = (us*)(ws + 58 * MB);
  us* h1h     = (us*)(ws + 60 * MB);   // 4MB
  us* h1l     = (us*)(ws + 64 * MB);   // 4MB
  float* h2   = (float*)(ws + 68 * MB);// 8MB

  // all input prep in one kernel
  k_pre<<<20480, 256, 0, stream>>>(x, xh, xl, xproj, anw, xn,
                                   wq, wk, wqkT, w1, w2, w1Th, w1Tl, w2Th, w2Tl);

  // fused Q|K projection + per-head rmsnorm -> Qnn/Knn bf16 (8-wave blocks)
  k_gemm_qk<<<dim3(32, 16), 512, 0, stream>>>(xn, wqkT, bq, bk, qnw, knw, Qnn, Knn, AHX);

  // scores: denominators then per-tile importance partials (rc inline)
  k_z<<<dim3(8, NHEAD, 4), 512, 0, stream>>>(Qnn, Knn, zpart);
  k_imp<<<dim3(8, NHEAD, 4), 512, 0, stream>>>(Qnn, Knn, zpart, imp_part);

  // router MLP (LDS-staged split-bf16 GEMMs, round-7 form)
  k_gemm_mlp<1><<<dim3(HIDX / 64, T_TOK / 64), 256, 0, stream>>>(
      xh, xl, w1Th, w1Tl, b1, nullptr, h1h, h1l, HIDX, DIMX);
  k_gemm_mlp<2><<<dim3(HIDX / 64, T_TOK / 64), 256, 0, stream>>>(
      h1h, h1l, w2Th, w2Tl, b2, h2, nullptr, nullptr, HIDX, HIDX);

  // importance reduction + router top-k
  k_final<<<8 + T_TOK / 4, 256, 0, stream>>>(imp_part, h2, w3, b3, out);

  (void)in_sizes; (void)n_in; (void)out_size; (void)ws_size;
}

// Round 10
// 181.531 us; speedup vs baseline: 1.5033x; 1.1782x over previous
//
#include <hip/hip_runtime.h>

#define T_TOK 2048
#define DIMX  1024
#define AHX   2048
#define HIDX  1024
#define NEXP  8
#define NHEAD 16
#define HD    128

typedef unsigned short us;
typedef short bf16x8 __attribute__((ext_vector_type(8)));
typedef float f32x4  __attribute__((ext_vector_type(4)));

__device__ __forceinline__ us f2bf(float f){
  unsigned int u = __builtin_bit_cast(unsigned int, f);
  u += 0x7FFFu + ((u >> 16) & 1u);          // RNE
  return (us)(u >> 16);
}
__device__ __forceinline__ float bf2f(us h){
  unsigned int u = ((unsigned int)h) << 16;
  return __builtin_bit_cast(float, u);
}
__device__ __forceinline__ float gelu_exact(float x){
  return 0.5f * x * (1.0f + erff(x * 0.70710678118654752440f));
}
__device__ __forceinline__ void gload16(const us* g, us* l){
  __builtin_amdgcn_global_load_lds((const __attribute__((address_space(1))) unsigned int*)g,
                                   (__attribute__((address_space(3))) unsigned int*)l, 16, 0, 0);
}

// ------------- pre: split_cast(x) + rmsnorm(xproj) + transpose wq/wk + transpose/split w1/w2 ---
__global__ __launch_bounds__(256) void k_pre(const float* __restrict__ x,
                                             us* __restrict__ xh, us* __restrict__ xl,
                                             const float* __restrict__ xproj,
                                             const float* __restrict__ anw,
                                             us* __restrict__ xn,
                                             const float* __restrict__ wq,
                                             const float* __restrict__ wk,
                                             us* __restrict__ wqkT,
                                             const float* __restrict__ w1,
                                             const float* __restrict__ w2,
                                             us* __restrict__ w1h, us* __restrict__ w1l,
                                             us* __restrict__ w2h, us* __restrict__ w2l){
  __shared__ float tile[32][33];
  __shared__ float ps[4];
  int bx = blockIdx.x, t = threadIdx.x;
  if (bx < 8192){
    int i = bx * 256 + t;
    float v = x[i];
    us h = f2bf(v);
    xh[i] = h;
    xl[i] = f2bf(v - bf2f(h));
    return;
  }
  if (bx < 10240){
    int row = bx - 8192;
    const float* p = xproj + (size_t)row * AHX;
    float v[8];
    *(float4*)&v[0] = *(const float4*)(p + t * 8);
    *(float4*)&v[4] = *(const float4*)(p + t * 8 + 4);
    float s = 0.f;
    #pragma unroll
    for (int i = 0; i < 8; i++) s += v[i] * v[i];
    #pragma unroll
    for (int m = 1; m < 64; m <<= 1) s += __shfl_xor(s, m);
    if ((t & 63) == 0) ps[t >> 6] = s;
    __syncthreads();
    float tot = ps[0] + ps[1] + ps[2] + ps[3];
    float rs = rsqrtf(tot * (1.0f / AHX) + 1e-6f);
    #pragma unroll
    for (int i = 0; i < 8; i++)
      xn[(size_t)row * AHX + t * 8 + i] = f2bf(v[i] * rs * anw[t * 8 + i]);
    return;
  }
  int tx = t & 31, ty = t >> 5;   // 32x8
  if (bx < 18432){
    int sub = bx - 10240;
    const float* in = (sub >> 12) ? wk : wq;
    us* o = wqkT + (size_t)(sub >> 12) * AHX * AHX;
    int rem = sub & 4095;
    int tbx = (rem & 63) * 32, tby = (rem >> 6) * 32;
    #pragma unroll
    for (int i = 0; i < 32; i += 8)
      tile[ty + i][tx] = in[(size_t)(tby + ty + i) * AHX + tbx + tx];
    __syncthreads();
    #pragma unroll
    for (int i = 0; i < 32; i += 8)
      o[(size_t)(tbx + ty + i) * AHX + tby + tx] = f2bf(tile[tx][ty + i]);
    return;
  }
  {
    int sub = bx - 18432;
    const float* in = (sub >> 10) ? w2 : w1;
    us* oh = (sub >> 10) ? w2h : w1h;
    us* ol = (sub >> 10) ? w2l : w1l;
    int rem = sub & 1023;
    int tbx = (rem & 31) * 32, tby = (rem >> 5) * 32;
    #pragma unroll
    for (int i = 0; i < 32; i += 8)
      tile[ty + i][tx] = in[(size_t)(tby + ty + i) * HIDX + tbx + tx];
    __syncthreads();
    #pragma unroll
    for (int i = 0; i < 32; i += 8){
      float v = tile[tx][ty + i];
      us h = f2bf(v);
      size_t o = (size_t)(tbx + ty + i) * DIMX + tby + tx;
      oh[o] = h;
      ol[o] = f2bf(v - bf2f(h));
    }
  }
}

// ------- fused Q|K projection GEMM + per-head rmsnorm epilogue, 8 waves -------
__global__ __launch_bounds__(512) void k_gemm_qk(
    const us* __restrict__ A, const us* __restrict__ B,
    const float* __restrict__ bq, const float* __restrict__ bk,
    const float* __restrict__ qnw, const float* __restrict__ knw,
    us* __restrict__ Qnn, us* __restrict__ Knn, int K)
{
  __shared__ __align__(16) us sA[2][128 * 64];
  __shared__ __align__(16) us sB[2][128 * 64];
  __shared__ float sums[128][4];
  int tid = threadIdx.x;
  int bm = blockIdx.y * 128;
  int bnB = blockIdx.x * 128;
  int w = tid >> 6, l = tid & 63;
  int wm = (w >> 2) * 64, wn = (w & 3) * 32;
  int lhi = l >> 4, llo = l & 15;
  int srow = l >> 3;
  int scol = ((l & 7) ^ srow) * 8;
  int swz = llo & 7;

  const us* pA = &A[(size_t)(bm + w * 16 + srow) * K + scol];
  const us* pB = &B[(size_t)(bnB + w * 16 + srow) * K + scol];

  f32x4 acc[4][2] = {};

  #pragma unroll
  for (int i = 0; i < 2; i++){
    gload16(pA + (size_t)i * 8 * K, &sA[0][(w * 16 + i * 8) * 64]);
    gload16(pB + (size_t)i * 8 * K, &sB[0][(w * 16 + i * 8) * 64]);
  }
  __syncthreads();

  int cur = 0;
  for (int k0 = 0; k0 < K; k0 += 64){
    if (k0 + 64 < K){
      #pragma unroll
      for (int i = 0; i < 2; i++){
        gload16(pA + (size_t)i * 8 * K + k0 + 64, &sA[cur ^ 1][(w * 16 + i * 8) * 64]);
        gload16(pB + (size_t)i * 8 * K + k0 + 64, &sB[cur ^ 1][(w * 16 + i * 8) * 64]);
      }
    }
    bf16x8 af[2][4], bfr[2][2];
    #pragma unroll
    for (int kk = 0; kk < 2; kk++){
      int ca = ((kk * 4 + lhi) ^ swz) * 8;
      #pragma unroll
      for (int m = 0; m < 4; m++)
        af[kk][m] = *(const bf16x8*)&sA[cur][(wm + m * 16 + llo) * 64 + ca];
      #pragma unroll
      for (int n = 0; n < 2; n++)
        bfr[kk][n] = *(const bf16x8*)&sB[cur][(wn + n * 16 + llo) * 64 + ca];
    }
    #pragma unroll
    for (int kk = 0; kk < 2; kk++)
      #pragma unroll
      for (int m = 0; m < 4; m++)
        #pragma unroll
        for (int n = 0; n < 2; n++)
          acc[m][n] = __builtin_amdgcn_mfma_f32_16x16x32_bf16(af[kk][m], bfr[kk][n], acc[m][n], 0, 0, 0);
    __syncthreads();
    cur ^= 1;
  }

  bool isq = blockIdx.x < 16;
  const float* bias = isq ? bq : bk;
  const float* nw   = isq ? qnw : knw;
  us* outp = isq ? Qnn : Knn;
  int hcol0 = (blockIdx.x & 15) * 128;

  #pragma unroll
  for (int n = 0; n < 2; n++){
    float bv = bias[hcol0 + wn + n * 16 + llo];
    #pragma unroll
    for (int m = 0; m < 4; m++)
      #pragma unroll
      for (int j = 0; j < 4; j++) acc[m][n][j] += bv;
  }
  #pragma unroll
  for (int m = 0; m < 4; m++)
    #pragma unroll
    for (int j = 0; j < 4; j++){
      float p = 0.f;
      #pragma unroll
      for (int n = 0; n < 2; n++) p += acc[m][n][j] * acc[m][n][j];
      p += __shfl_xor(p, 1); p += __shfl_xor(p, 2);
      p += __shfl_xor(p, 4); p += __shfl_xor(p, 8);
      if (llo == 0) sums[wm + m * 16 + lhi * 4 + j][w & 3] = p;
    }
  __syncthreads();
  #pragma unroll
  for (int m = 0; m < 4; m++)
    #pragma unroll
    for (int j = 0; j < 4; j++){
      int row = wm + m * 16 + lhi * 4 + j;
      float rs = rsqrtf((sums[row][0] + sums[row][1] + sums[row][2] + sums[row][3]) * (1.0f / HD) + 1e-6f);
      #pragma unroll
      for (int n = 0; n < 2; n++){
        int col = wn + n * 16 + llo;
        outp[(size_t)(bm + row) * AHX + hcol0 + col] = f2bf(acc[m][n][j] * rs * nw[col]);
      }
    }
}

// -------- MLP GEMM: C[M,N] = A*B^T (+bias, epilogue), split-bf16 fp32 emulation ---------
// BM=64, BN=64, BK=64; dbuf gload_lds, swizzled source/read. (round-7 proven form)
template<int EPI>
__global__ __launch_bounds__(256) void k_gemm_mlp(
    const us* __restrict__ Ah_, const us* __restrict__ Al_,
    const us* __restrict__ Bh_, const us* __restrict__ Bl_,
    const float* __restrict__ bias,
    float* __restrict__ Cf, us* __restrict__ Ch, us* __restrict__ Cl,
    int N, int K)
{
  __shared__ __align__(16) us sAh[2][64 * 64], sAl[2][64 * 64];
  __shared__ __align__(16) us sBh[2][64 * 64], sBl[2][64 * 64];
  int tid = threadIdx.x;
  int bm = blockIdx.y * 64, bn = blockIdx.x * 64;
  int w = tid >> 6, l = tid & 63;
  int wm = (w >> 1) * 32, wn = (w & 1) * 32;
  int lhi = l >> 4, llo = l & 15;
  int srow = l >> 3;
  int scol = ((l & 7) ^ srow) * 8;
  int swz = llo & 7;

  const us* pAh = &Ah_[(size_t)(bm + w * 8 + srow) * K + scol];
  const us* pAl = &Al_[(size_t)(bm + w * 8 + srow) * K + scol];
  const us* pBh = &Bh_[(size_t)(bn + w * 8 + srow) * K + scol];
  const us* pBl = &Bl_[(size_t)(bn + w * 8 + srow) * K + scol];

  f32x4 acc[2][2] = {};

  auto stage = [&](int buf, int k0){
    #pragma unroll
    for (int i = 0; i < 2; i++){
      int rb = (i * 32 + w * 8) * 64;
      gload16(pAh + (size_t)i * 32 * K + k0, &sAh[buf][rb]);
      gload16(pAl + (size_t)i * 32 * K + k0, &sAl[buf][rb]);
      gload16(pBh + (size_t)i * 32 * K + k0, &sBh[buf][rb]);
      gload16(pBl + (size_t)i * 32 * K + k0, &sBl[buf][rb]);
    }
  };

  stage(0, 0);
  __syncthreads();

  int cur = 0;
  for (int k0 = 0; k0 < K; k0 += 64){
    if (k0 + 64 < K) stage(cur ^ 1, k0 + 64);
    bf16x8 ah[2][2], al[2][2], bh[2][2], bl[2][2];
    #pragma unroll
    for (int kk = 0; kk < 2; kk++){
      int ca = ((kk * 4 + lhi) ^ swz) * 8;
      #pragma unroll
      for (int m = 0; m < 2; m++){
        ah[kk][m] = *(const bf16x8*)&sAh[cur][(wm + m * 16 + llo) * 64 + ca];
        al[kk][m] = *(const bf16x8*)&sAl[cur][(wm + m * 16 + llo) * 64 + ca];
        bh[kk][m] = *(const bf16x8*)&sBh[cur][(wn + m * 16 + llo) * 64 + ca];
        bl[kk][m] = *(const bf16x8*)&sBl[cur][(wn + m * 16 + llo) * 64 + ca];
      }
    }
    #pragma unroll
    for (int kk = 0; kk < 2; kk++)
      #pragma unroll
      for (int m = 0; m < 2; m++)
        #pragma unroll
        for (int n = 0; n < 2; n++){
          acc[m][n] = __builtin_amdgcn_mfma_f32_16x16x32_bf16(ah[kk][m], bh[kk][n], acc[m][n], 0, 0, 0);
          acc[m][n] = __builtin_amdgcn_mfma_f32_16x16x32_bf16(ah[kk][m], bl[kk][n], acc[m][n], 0, 0, 0);
          acc[m][n] = __builtin_amdgcn_mfma_f32_16x16x32_bf16(al[kk][m], bh[kk][n], acc[m][n], 0, 0, 0);
        }
    __syncthreads();
    cur ^= 1;
  }

  #pragma unroll
  for (int m = 0; m < 2; m++)
    #pragma unroll
    for (int n = 0; n < 2; n++){
      int col = bn + wn + n * 16 + llo;
      float bv = bias[col];
      #pragma unroll
      for (int j = 0; j < 4; j++){
        int row = bm + wm + m * 16 + lhi * 4 + j;
        float v = acc[m][n][j] + bv;
        size_t off = (size_t)row * N + col;
        if constexpr (EPI == 1){
          float g = gelu_exact(v);
          us hh = f2bf(g);
          Ch[off] = hh;
          Cl[off] = f2bf(g - bf2f(hh));
        } else {
          Cf[off] = gelu_exact(v);
        }
      }
    }
}

// XCD-grouping decode for 2048-block score kernels (flat 1-D grid):
// d = ghi*128 + m*8 + glo ; g = ghi*8+glo = h + 16*z ; member m = qb index.
// All 16 qb sharing (h,z), and all z of a given h, land on XCD h%8 -> K and Q
// panels fetch once per XCD (2MB working set < 4MB L2).
__device__ __forceinline__ void score_decode(int d, int& qb_i, int& h, int& zc){
  int glo = d & 7, m = (d >> 3) & 15, ghi = d >> 7;
  int g = ghi * 8 + glo;
  h = g & 15; zc = g >> 4; qb_i = m;
}

// ---------------- scores denominator: zpart[z][h][row], 8 waves, 16 q-rows/wave ----------------
__global__ __launch_bounds__(512) void k_z(const us* __restrict__ Qn,
                                           const us* __restrict__ Kn,
                                           float* __restrict__ zpart){
  __shared__ __align__(16) us sK[2][128 * 128];
  int qb_i, h, zc;
  score_decode(blockIdx.x, qb_i, h, zc);
  int qb = qb_i * 128;
  int tid = threadIdx.x, w = tid >> 6, l = tid & 63;
  int lhi = l >> 4, llo = l & 15;
  int wq = qb + w * 16;
  const float scale = 0.08838834764831845f;

  auto stageK = [&](int buf, int kt){
    #pragma unroll
    for (int i = 0; i < 4; i++){
      int rb = w * 16 + i * 4;
      int r = rb + lhi;
      int c = (llo ^ (r & 7)) * 8;
      gload16(&Kn[(size_t)(kt + r) * AHX + h * HD + c], &sK[buf][rb * 128]);
    }
  };

  bf16x8 qf[4];
  #pragma unroll
  for (int kk = 0; kk < 4; kk++)
    qf[kk] = *(const bf16x8*)&Qn[(size_t)(wq + llo) * AHX + h * HD + kk * 32 + lhi * 8];

  float rz[4] = {};
  int kt0 = zc * 256;

  stageK(0, kt0);
  __syncthreads();

  #pragma unroll
  for (int t = 0; t < 2; t++){
    if (t == 0) stageK(1, kt0 + 128);
    f32x4 acc[8] = {};
    #pragma unroll
    for (int n = 0; n < 8; n++){
      int row = n * 16 + llo;
      #pragma unroll
      for (int kk = 0; kk < 4; kk++){
        bf16x8 kf = *(const bf16x8*)&sK[t][row * 128 + ((kk * 32 + lhi * 8) ^ ((llo & 7) << 3))];
        acc[n] = __builtin_amdgcn_mfma_f32_16x16x32_bf16(qf[kk], kf, acc[n], 0, 0, 0);
      }
    }
    #pragma unroll
    for (int j = 0; j < 4; j++){
      float s = 0.f;
      #pragma unroll
      for (int n = 0; n < 8; n++) s += __expf(acc[n][j] * scale);
      rz[j] += s;
    }
    if (t == 0) __syncthreads();
  }
  #pragma unroll
  for (int j = 0; j < 4; j++){
    float s = rz[j];
    s += __shfl_xor(s, 1); s += __shfl_xor(s, 2);
    s += __shfl_xor(s, 4); s += __shfl_xor(s, 8);
    if (llo == 0){
      int row = wq + lhi * 4 + j;
      zpart[(size_t)zc * (NHEAD * T_TOK) + h * T_TOK + row] = s;
    }
  }
}

// ---------------- importance partials: 8 waves, inline rc gather ----------------
__global__ __launch_bounds__(512) void k_imp(const us* __restrict__ Qn,
                                             const us* __restrict__ Kn,
                                             const float* __restrict__ zpart,
                                             float* __restrict__ imp_part){
  __shared__ __align__(16) us sK[2][128 * 128];
  __shared__ float simp[8][128];
  int qb_i, h, zc;
  score_decode(blockIdx.x, qb_i, h, zc);
  int qb = qb_i * 128;
  int kt0 = zc * 256;
  int tid = threadIdx.x, w = tid >> 6, l = tid & 63;
  int lhi = l >> 4, llo = l & 15;
  int wq = qb + w * 16;
  const float scale = 0.08838834764831845f;

  auto stageK = [&](int buf, int kt){
    #pragma unroll
    for (int i = 0; i < 4; i++){
      int rb = w * 16 + i * 4;
      int r = rb + lhi;
      int c = (llo ^ (r & 7)) * 8;
      gload16(&Kn[(size_t)(kt + r) * AHX + h * HD + c], &sK[buf][rb * 128]);
    }
  };

  bf16x8 qf[4];
  float rcv[4];
  #pragma unroll
  for (int kk = 0; kk < 4; kk++)
    qf[kk] = *(const bf16x8*)&Qn[(size_t)(wq + llo) * AHX + h * HD + kk * 32 + lhi * 8];
  #pragma unroll
  for (int j = 0; j < 4; j++){
    int row = wq + lhi * 4 + j;
    float zs = 0.f;
    #pragma unroll
    for (int p = 0; p < 8; p++) zs += zpart[(size_t)p * (NHEAD * T_TOK) + h * T_TOK + row];
    rcv[j] = 1.0f / ((float)NHEAD * zs);
  }

  stageK(0, kt0);
  __syncthreads();

  #pragma unroll
  for (int t = 0; t < 2; t++){
    if (t == 0) stageK(1, kt0 + 128);
    f32x4 acc[8] = {};
    #pragma unroll
    for (int n = 0; n < 8; n++){
      int row = n * 16 + llo;
      #pragma unroll
      for (int kk = 0; kk < 4; kk++){
        bf16x8 kf = *(const bf16x8*)&sK[t][row * 128 + ((kk * 32 + lhi * 8) ^ ((llo & 7) << 3))];
        acc[n] = __builtin_amdgcn_mfma_f32_16x16x32_bf16(qf[kk], kf, acc[n], 0, 0, 0);
      }
    }
    #pragma unroll
    for (int n = 0; n < 8; n++){
      float s = 0.f;
      #pragma unroll
      for (int j = 0; j < 4; j++) s += __expf(acc[n][j] * scale) * rcv[j];
      s += __shfl_xor(s, 16);
      s += __shfl_xor(s, 32);
      if (l < 16) simp[w][n * 16 + l] = s;
    }
    __syncthreads();
    if (tid < 128){
      float tot = 0.f;
      #pragma unroll
      for (int ww = 0; ww < 8; ww++) tot += simp[ww][tid];
      imp_part[((size_t)qb_i * NHEAD + h) * T_TOK + kt0 + t * 128 + tid] = tot;
    }
    __syncthreads();
  }
}

// ---------------- final: impred [blocks 0..7] + router [8..519] ----------------
__global__ __launch_bounds__(256) void k_final(const float* __restrict__ imp_part,
                                               const float* __restrict__ h2,
                                               const float* __restrict__ w3,
                                               const float* __restrict__ b3,
                                               float* __restrict__ out){
  if (blockIdx.x < 8){
    int col = blockIdx.x * 256 + threadIdx.x;
    float s = 0.f;
    for (int r = 0; r < 256; r++) s += imp_part[(size_t)r * T_TOK + col];
    out[2 * T_TOK + col] = s;
    return;
  }
  int t = (blockIdx.x - 8) * 4 + (threadIdx.x >> 6);
  int l = threadIdx.x & 63;
  const float* hp = h2 + (size_t)t * HIDX;
  float acc[NEXP] = {};
  for (int i = l; i < HIDX; i += 64){
    float hv = hp[i];
    const float* wr = w3 + (size_t)i * NEXP;
    #pragma unroll
    for (int e = 0; e < NEXP; e++) acc[e] = fmaf(hv, wr[e], acc[e]);
  }
  #pragma unroll
  for (int mk = 1; mk < 64; mk <<= 1)
    #pragma unroll
    for (int e = 0; e < NEXP; e++) acc[e] += __shfl_xor(acc[e], mk);
  if (l == 0){
    float lg[NEXP], mx = -__builtin_inff();
    #pragma unroll
    for (int e = 0; e < NEXP; e++){ lg[e] = acc[e] + b3[e]; mx = fmaxf(mx, lg[e]); }
    float Z = 0.f, p[NEXP];
    #pragma unroll
    for (int e = 0; e < NEXP; e++){ p[e] = expf(lg[e] - mx); Z += p[e]; }
    float invZ = 1.0f / Z;
    #pragma unroll
    for (int e = 0; e < NEXP; e++) p[e] *= invZ;
    float gs[4];
    #pragma unroll
    for (int g = 0; g < 4; g++) gs[g] = fmaxf(p[2 * g], p[2 * g + 1]);
    int g1 = 0;
    #pragma unroll
    for (int g = 1; g < 4; g++) if (gs[g] > gs[g1]) g1 = g;
    int g2 = -1; float g2v = -__builtin_inff();
    #pragma unroll
    for (int g = 0; g < 4; g++) if (g != g1 && gs[g] > g2v){ g2v = gs[g]; g2 = g; }
    int best = 0; float bv = -__builtin_inff();
    #pragma unroll
    for (int e = 0; e < NEXP; e++){
      int g = e >> 1;
      if ((g == g1 || g == g2) && p[e] > bv){ bv = p[e]; best = e; }
    }
    out[t]         = bv;            // ROUTE_SCALE = 1.0
    out[T_TOK + t] = (float)best;   // idx as float
  }
}

// ---------------- driver ----------------
extern "C" void kernel_launch(void* const* d_in, const int* in_sizes, int n_in,
                              void* d_out, int out_size, void* d_ws, size_t ws_size,
                              hipStream_t stream){
  const float* x     = (const float*)d_in[0];
  const float* xproj = (const float*)d_in[1];
  const float* anw   = (const float*)d_in[2];
  const float* wq    = (const float*)d_in[3];
  const float* bq    = (const float*)d_in[4];
  const float* wk    = (const float*)d_in[5];
  const float* bk    = (const float*)d_in[6];
  const float* qnw   = (const float*)d_in[7];
  const float* knw   = (const float*)d_in[8];
  const float* w1    = (const float*)d_in[9];
  const float* b1    = (const float*)d_in[10];
  const float* w2    = (const float*)d_in[11];
  const float* b2    = (const float*)d_in[12];
  const float* w3    = (const float*)d_in[13];
  const float* b3    = (const float*)d_in[14];
  float* out = (float*)d_out;

  char* ws = (char*)d_ws;
  const size_t MB = 1024 * 1024;
  us* xn      = (us*)(ws);             // 8MB  [T][AHX] bf16
  us* wqkT    = (us*)(ws + 8 * MB);    // 16MB [4096][2048] bf16
  us* Qnn     = (us*)(ws + 24 * MB);   // 8MB
  us* Knn     = (us*)(ws + 32 * MB);   // 8MB
  float* zpart    = (float*)(ws + 40 * MB);  // 1MB [8][16][2048]
  float* imp_part = (float*)(ws + 42 * MB);  // 2MB [256][2048]
  us* xh      = (us*)(ws + 44 * MB);   // 4MB
  us* xl      = (us*)(ws + 48 * MB);   // 4MB
  us* w1Th    = (us*)(ws + 52 * MB);   // 2MB each
  us* w1Tl    = (us*)(ws + 54 * MB);
  us* w2Th    = (us*)(ws + 56 * MB);
  us* w2Tl    = (us*)(ws + 58 * MB);
  us* h1h     = (us*)(ws + 60 * MB);   // 4MB
  us* h1l     = (us*)(ws + 64 * MB);   // 4MB
  float* h2   = (float*)(ws + 68 * MB);// 8MB

  // all input prep in one kernel
  k_pre<<<20480, 256, 0, stream>>>(x, xh, xl, xproj, anw, xn,
                                   wq, wk, wqkT, w1, w2, w1Th, w1Tl, w2Th, w2Tl);

  // fused Q|K projection + per-head rmsnorm -> Qnn/Knn bf16 (8-wave blocks)
  k_gemm_qk<<<dim3(32, 16), 512, 0, stream>>>(xn, wqkT, bq, bk, qnw, knw, Qnn, Knn, AHX);

  // scores: denominators then per-tile importance partials (XCD-grouped flat grids)
  k_z<<<2048, 512, 0, stream>>>(Qnn, Knn, zpart);
  k_imp<<<2048, 512, 0, stream>>>(Qnn, Knn, zpart, imp_part);

  // router MLP (LDS-staged split-bf16 GEMMs, round-7 form)
  k_gemm_mlp<1><<<dim3(HIDX / 64, T_TOK / 64), 256, 0, stream>>>(
      xh, xl, w1Th, w1Tl, b1, nullptr, h1h, h1l, HIDX, DIMX);
  k_gemm_mlp<2><<<dim3(HIDX / 64, T_TOK / 64), 256, 0, stream>>>(
      h1h, h1l, w2Th, w2Tl, b2, h2, nullptr, nullptr, HIDX, HIDX);

  // importance reduction + router top-k
  k_final<<<8 + T_TOK / 4, 256, 0, stream>>>(imp_part, h2, w3, b3, out);

  (void)in_sizes; (void)n_in; (void)out_size; (void)ws_size;
}